// Round 1
// baseline (184.942 us; speedup 1.0000x reference)
//
#include <hip/hip_runtime.h>

#define T_STEPS 2048
#define NI 4096
#define NO 4096

static constexpr float BETA = 0.9f;
static constexpr float THRESH = 1.0f;

// Workspace layout in d_ws
struct Ws {
  int tstar;                 // global first spike step (min over neurons)
  int pad;
  unsigned long long packed; // winner key: ((noise_bits>>9) << 32) | (NO-1-o)
  int fst[NO];               // per-neuron first spike step (T_STEPS if none)
};

// ---- Threefry-2x32, key = (0, 42), matching JAX's threefry2x32 ----
__device__ inline void threefry2x32(unsigned k0, unsigned k1,
                                    unsigned& x0, unsigned& x1) {
  const unsigned k2 = k0 ^ k1 ^ 0x1BD11BDAu;
  x0 += k0; x1 += k1;
#define TF_RND(r) { x0 += x1; x1 = (x1 << (r)) | (x1 >> (32 - (r))); x1 ^= x0; }
  TF_RND(13) TF_RND(15) TF_RND(26) TF_RND(6)
  x0 += k1; x1 += k2 + 1u;
  TF_RND(17) TF_RND(29) TF_RND(16) TF_RND(24)
  x0 += k2; x1 += k0 + 2u;
  TF_RND(13) TF_RND(15) TF_RND(26) TF_RND(6)
  x0 += k0; x1 += k1 + 3u;
  TF_RND(17) TF_RND(29) TF_RND(16) TF_RND(24)
  x0 += k1; x1 += k2 + 4u;
  TF_RND(13) TF_RND(15) TF_RND(26) TF_RND(6)
  x0 += k2; x1 += k0 + 5u;
#undef TF_RND
}

__global__ void k_init(Ws* ws) {
  ws->tstar = T_STEPS;
  ws->packed = 0ull;
}

// One wave (64 lanes) per neuron. W row hoisted into registers (16 float4).
// Simulate until this neuron's own first spike; record mem rows as we go.
__global__ __launch_bounds__(256) void k_sim(const float* __restrict__ x,
                                             const float* __restrict__ W,
                                             float* __restrict__ mem_rec,
                                             Ws* __restrict__ ws) {
  const int wid  = (int)((blockIdx.x * blockDim.x + threadIdx.x) >> 6);
  const int lane = (int)(threadIdx.x & 63);
  if (wid >= NO) return;

  const float4* Wrow = reinterpret_cast<const float4*>(W) + (size_t)wid * (NI / 4);
  float4 w[16];
#pragma unroll
  for (int j = 0; j < 16; ++j) w[j] = Wrow[j * 64 + lane];

  float mem = 0.0f;
  int my_fst = T_STEPS;

  for (int t = 0; t < T_STEPS; ++t) {
    const float4* xr = reinterpret_cast<const float4*>(x) + (size_t)t * (NI / 4);
    float acc = 0.0f;
#pragma unroll
    for (int j = 0; j < 16; ++j) {
      float4 xv = xr[j * 64 + lane];
      acc += xv.x * w[j].x;
      acc += xv.y * w[j].y;
      acc += xv.z * w[j].z;
      acc += xv.w * w[j].w;
    }
    // full-wave butterfly reduce: every lane ends with the total
#pragma unroll
    for (int off = 32; off >= 1; off >>= 1) acc += __shfl_xor(acc, off, 64);

    const float reset = (mem > THRESH) ? THRESH : 0.0f;
    mem = BETA * mem + acc - reset;

    if (lane == 0) mem_rec[(size_t)t * NO + wid] = mem;
    if (mem > THRESH) { my_fst = t; break; }
  }

  if (lane == 0) {
    ws->fst[wid] = my_fst;
    atomicMin(&ws->tstar, my_fst);
  }
}

// Zero mem rows written past t*; compute winner candidates (fst[o] == t*).
__global__ void k_fix(float* __restrict__ mem_rec, Ws* __restrict__ ws) {
  const int o = blockIdx.x * blockDim.x + threadIdx.x;
  if (o >= NO) return;
  const int ts = ws->tstar;
  const int f  = ws->fst[o];
  for (int t = ts + 1; t <= f && t < T_STEPS; ++t)
    mem_rec[(size_t)t * NO + o] = 0.0f;

  if (ts < T_STEPS && f == ts) {
    // noise[ts][o] = uniform bits at flat index i = ts*NO + o
    const unsigned H = (unsigned)T_STEPS * (unsigned)NO / 2u; // 4194304
    const unsigned i = (unsigned)ts * (unsigned)NO + (unsigned)o;
    unsigned c0 = (i < H) ? i : (i - H);
    unsigned c1 = (i < H) ? (i + H) : i;
    threefry2x32(0u, 42u, c0, c1);
    const unsigned bits = (i < H) ? c0 : c1;
    const unsigned mant = bits >> 9; // monotone in the final uniform float
    const unsigned long long key =
        ((unsigned long long)mant << 32) | (unsigned)(NO - 1 - o);
    atomicMax(&ws->packed, key);
  }
}

__global__ void k_winner(float* __restrict__ spk_rec, Ws* __restrict__ ws) {
  if (threadIdx.x == 0 && blockIdx.x == 0) {
    const int ts = ws->tstar;
    if (ts < T_STEPS) {
      const unsigned o =
          (unsigned)(NO - 1) - (unsigned)(ws->packed & 0xFFFFFFFFull);
      spk_rec[(size_t)ts * NO + o] = 1.0f;
    }
  }
}

extern "C" void kernel_launch(void* const* d_in, const int* in_sizes, int n_in,
                              void* d_out, int out_size, void* d_ws, size_t ws_size,
                              hipStream_t stream) {
  const float* x = (const float*)d_in[0]; // [T, NI]
  const float* W = (const float*)d_in[1]; // [NO, NI]
  float* spk = (float*)d_out;                          // output 0: [T, NO]
  float* mem = (float*)d_out + (size_t)T_STEPS * NO;   // output 1: [T, NO]
  Ws* ws = (Ws*)d_ws;

  hipMemsetAsync(d_out, 0, (size_t)out_size * sizeof(float), stream);
  k_init<<<1, 1, 0, stream>>>(ws);
  k_sim<<<(NO * 64) / 256, 256, 0, stream>>>(x, W, mem, ws);
  k_fix<<<NO / 256, 256, 0, stream>>>(mem, ws);
  k_winner<<<1, 64, 0, stream>>>(spk, ws);
}

// Round 2
// 45.694 us; speedup vs baseline: 4.0474x; 4.0474x over previous
//
#include <hip/hip_runtime.h>

#define T_STEPS 2048
#define NI 4096
#define NO 4096

static constexpr float BETA = 0.9f;
static constexpr float THRESH = 1.0f;

// Workspace layout in d_ws
struct Ws {
  int tstar;                 // global first spike step (min over neurons)
  int pad;
  unsigned long long packed; // winner key: ((noise_bits>>9) << 32) | (NO-1-o)
  float cur0[NO];            // cur at t=0 (for general-path restart)
  int fst[NO];               // per-neuron first spike step (T_STEPS if none)
  int wmax[NO];              // highest mem_rec row actually written per neuron
};

// ---- Threefry-2x32, key = (0, 42), matching JAX's threefry2x32 ----
__device__ inline void threefry2x32(unsigned k0, unsigned k1,
                                    unsigned& x0, unsigned& x1) {
  const unsigned k2 = k0 ^ k1 ^ 0x1BD11BDAu;
  x0 += k0; x1 += k1;
#define TF_RND(r) { x0 += x1; x1 = (x1 << (r)) | (x1 >> (32 - (r))); x1 ^= x0; }
  TF_RND(13) TF_RND(15) TF_RND(26) TF_RND(6)
  x0 += k1; x1 += k2 + 1u;
  TF_RND(17) TF_RND(29) TF_RND(16) TF_RND(24)
  x0 += k2; x1 += k0 + 2u;
  TF_RND(13) TF_RND(15) TF_RND(26) TF_RND(6)
  x0 += k0; x1 += k1 + 3u;
  TF_RND(17) TF_RND(29) TF_RND(16) TF_RND(24)
  x0 += k1; x1 += k2 + 4u;
  TF_RND(13) TF_RND(15) TF_RND(26) TF_RND(6)
  x0 += k2; x1 += k0 + 5u;
#undef TF_RND
}

__global__ void k_init(Ws* ws) {
  ws->tstar = T_STEPS;
  ws->packed = 0ull;
}

// One wave per neuron: cur0[o] = x[0]·W[o]. Row 0 of mem_rec is ALWAYS
// recorded (done starts False), and if anyone spikes at t=0 then tstar=0
// and the whole remaining output is zeros + one one-hot.
__global__ __launch_bounds__(256) void k_gemv0(const float* __restrict__ x,
                                               const float* __restrict__ W,
                                               float* __restrict__ mem_rec,
                                               Ws* __restrict__ ws) {
  const int wid  = (int)((blockIdx.x * blockDim.x + threadIdx.x) >> 6);
  const int lane = (int)(threadIdx.x & 63);
  if (wid >= NO) return;

  const float4* Wrow = reinterpret_cast<const float4*>(W) + (size_t)wid * (NI / 4);
  const float4* xr   = reinterpret_cast<const float4*>(x); // row 0

  float acc = 0.0f;
#pragma unroll
  for (int j = 0; j < 16; ++j) {
    float4 wv = Wrow[j * 64 + lane];
    float4 xv = xr[j * 64 + lane];
    acc += xv.x * wv.x;
    acc += xv.y * wv.y;
    acc += xv.z * wv.z;
    acc += xv.w * wv.w;
  }
#pragma unroll
  for (int off = 32; off >= 1; off >>= 1) acc += __shfl_xor(acc, off, 64);

  if (lane == 0) {
    mem_rec[wid] = acc;       // row 0
    ws->cur0[wid] = acc;
    const int f = (acc > THRESH) ? 0 : T_STEPS;
    ws->fst[wid] = f;
    ws->wmax[wid] = 0;
    if (f == 0) atomicMin(&ws->tstar, 0);
  }
}

// General-path fallback: only runs if NO neuron spiked at t=0 (never, for the
// benchmark input — exits immediately). One wave per neuron, simulate from
// t=1 until own first spike.
__global__ __launch_bounds__(256) void k_slow(const float* __restrict__ x,
                                              const float* __restrict__ W,
                                              float* __restrict__ mem_rec,
                                              Ws* __restrict__ ws) {
  if (ws->tstar == 0) return;

  const int wid  = (int)((blockIdx.x * blockDim.x + threadIdx.x) >> 6);
  const int lane = (int)(threadIdx.x & 63);
  if (wid >= NO) return;

  const float4* Wrow = reinterpret_cast<const float4*>(W) + (size_t)wid * (NI / 4);
  float4 w[16];
#pragma unroll
  for (int j = 0; j < 16; ++j) w[j] = Wrow[j * 64 + lane];

  float mem = ws->cur0[wid];
  int my_fst = T_STEPS;
  int wmax = 0;

  for (int t = 1; t < T_STEPS; ++t) {
    const float4* xr = reinterpret_cast<const float4*>(x) + (size_t)t * (NI / 4);
    float acc = 0.0f;
#pragma unroll
    for (int j = 0; j < 16; ++j) {
      float4 xv = xr[j * 64 + lane];
      acc += xv.x * w[j].x;
      acc += xv.y * w[j].y;
      acc += xv.z * w[j].z;
      acc += xv.w * w[j].w;
    }
#pragma unroll
    for (int off = 32; off >= 1; off >>= 1) acc += __shfl_xor(acc, off, 64);

    const float reset = (mem > THRESH) ? THRESH : 0.0f;
    mem = BETA * mem + acc - reset;

    if (lane == 0) mem_rec[(size_t)t * NO + wid] = mem;
    wmax = t;
    if (mem > THRESH) { my_fst = t; break; }
  }

  if (lane == 0) {
    ws->fst[wid] = my_fst;
    ws->wmax[wid] = wmax;
    atomicMin(&ws->tstar, my_fst);
  }
}

// Zero rows written past t*; pick winner candidates (fst[o] == t*).
__global__ void k_fix(float* __restrict__ mem_rec, Ws* __restrict__ ws) {
  const int o = blockIdx.x * blockDim.x + threadIdx.x;
  if (o >= NO) return;
  const int ts = ws->tstar;
  const int wm = ws->wmax[o];
  for (int t = ts + 1; t <= wm; ++t)
    mem_rec[(size_t)t * NO + o] = 0.0f;

  if (ts < T_STEPS && ws->fst[o] == ts) {
    // noise[ts][o] = uniform bits at flat index i = ts*NO + o
    const unsigned H = (unsigned)T_STEPS * (unsigned)NO / 2u; // 4194304
    const unsigned i = (unsigned)ts * (unsigned)NO + (unsigned)o;
    unsigned c0 = (i < H) ? i : (i - H);
    unsigned c1 = (i < H) ? (i + H) : i;
    threefry2x32(0u, 42u, c0, c1);
    const unsigned bits = (i < H) ? c0 : c1;
    const unsigned mant = bits >> 9; // monotone in the final uniform float
    const unsigned long long key =
        ((unsigned long long)mant << 32) | (unsigned)(NO - 1 - o);
    atomicMax(&ws->packed, key);
  }
}

__global__ void k_winner(float* __restrict__ spk_rec, Ws* __restrict__ ws) {
  if (threadIdx.x == 0 && blockIdx.x == 0) {
    const int ts = ws->tstar;
    if (ts < T_STEPS) {
      const unsigned o =
          (unsigned)(NO - 1) - (unsigned)(ws->packed & 0xFFFFFFFFull);
      spk_rec[(size_t)ts * NO + o] = 1.0f;
    }
  }
}

extern "C" void kernel_launch(void* const* d_in, const int* in_sizes, int n_in,
                              void* d_out, int out_size, void* d_ws, size_t ws_size,
                              hipStream_t stream) {
  const float* x = (const float*)d_in[0]; // [T, NI]
  const float* W = (const float*)d_in[1]; // [NO, NI]
  float* spk = (float*)d_out;                          // output 0: [T, NO]
  float* mem = (float*)d_out + (size_t)T_STEPS * NO;   // output 1: [T, NO]
  Ws* ws = (Ws*)d_ws;

  hipMemsetAsync(d_out, 0, (size_t)out_size * sizeof(float), stream);
  k_init<<<1, 1, 0, stream>>>(ws);
  k_gemv0<<<(NO * 64) / 256, 256, 0, stream>>>(x, W, mem, ws);
  k_slow<<<(NO * 64) / 256, 256, 0, stream>>>(x, W, mem, ws);
  k_fix<<<NO / 256, 256, 0, stream>>>(mem, ws);
  k_winner<<<1, 64, 0, stream>>>(spk, ws);
}